// Round 10
// baseline (2024.275 us; speedup 1.0000x reference)
//
#include <hip/hip_runtime.h>

typedef __attribute__((ext_vector_type(4))) float f32x4;
typedef __attribute__((ext_vector_type(8))) short bf16x8;

#define MFMA(a, b, c) __builtin_amdgcn_mfma_f32_16x16x32_bf16(a, b, c, 0, 0, 0)

static __device__ __forceinline__ float bf2f(short h) {
  union { unsigned u; float f; } v; v.u = ((unsigned)(unsigned short)h) << 16;
  return v.f;
}
static __device__ __forceinline__ void split2(float x, short& hi, short& lo) {
  union { float f; unsigned u; } v; v.f = x;
  unsigned uh = v.u & 0xFFFF0000u;
  hi = (short)(uh >> 16);
  union { unsigned u; float f; } w; w.u = uh;
  union { float f; unsigned u; } z; z.f = x - w.f;
  lo = (short)((z.u + 0x7FFFu + ((z.u >> 16) & 1u)) >> 16);
}

__global__ void prep_w(const float* __restrict__ W0, const float* __restrict__ W1,
                       const float* __restrict__ W2, const float* __restrict__ W3,
                       const float* __restrict__ W4, const float* __restrict__ W5,
                       const float* __restrict__ W6, const float* __restrict__ W7,
                       short* __restrict__ ws) {
  const float* W[8] = {W0, W1, W2, W3, W4, W5, W6, W7};
  int t = blockIdx.x * 256 + threadIdx.x;
  int lane = t & 63, fragid = (t >> 6) & 7, mat = t >> 9;
  const float* Wm = W[mat];
  int ct = fragid >> 1, kh = fragid & 1;
  int wcol = ct * 16 + (lane & 15);
  int k0 = kh * 32 + ((lane >> 4) << 3);
  bf16x8 vh, vl;
#pragma unroll
  for (int j = 0; j < 8; ++j) {
    short h, l;
    split2(Wm[(k0 + j) * 64 + wcol], h, l);
    vh[j] = h; vl[j] = l;
  }
  size_t base = ((size_t)(mat * 16) + fragid) * 512 + lane * 8;
  *(bf16x8*)(ws + base) = vh;
  *(bf16x8*)(ws + base + 4096) = vl;
}

static __device__ __forceinline__ f32x4 gemm3(const bf16x8 (&ah)[2], const bf16x8 (&al)[2],
                                              const short* __restrict__ ws, int mat, int ct,
                                              int lane, f32x4 acc) {
#pragma unroll
  for (int kh = 0; kh < 2; ++kh) {
    const bf16x8 bh = *(const bf16x8*)(ws + ((size_t)(mat * 16) + ct * 2 + kh) * 512 + lane * 8);
    const bf16x8 bl = *(const bf16x8*)(ws + ((size_t)(mat * 16 + 8) + ct * 2 + kh) * 512 + lane * 8);
    acc = MFMA(ah[kh], bh, acc);
    acc = MFMA(al[kh], bh, acc);
    acc = MFMA(ah[kh], bl, acc);
  }
  return acc;
}

static __device__ __forceinline__ void ldpair(const short* lds_s, int plane_hi, int arow, int lane,
                                              bf16x8 (&ah)[2], bf16x8 (&al)[2]) {
#pragma unroll
  for (int kh = 0; kh < 2; ++kh) {
    int off = arow * 72 + kh * 32 + ((lane >> 4) << 3);
    ah[kh] = *(const bf16x8*)(lds_s + plane_hi * 4608 + off);
    al[kh] = *(const bf16x8*)(lds_s + (plane_hi + 1) * 4608 + off);
  }
}

#define CHK(a, b) (fabsf((a) - (b)) > 0.05f + 2e-3f * fabsf(b))

__global__ __launch_bounds__(256, 2) void fused_tp(
    const float* __restrict__ x1, const float* __restrict__ edge,
    const float* __restrict__ tp, const float* __restrict__ node,
    const short* __restrict__ ws,
    const float* __restrict__ Wg0, const float* __restrict__ Wg1,
    const float* __restrict__ Wg2, const float* __restrict__ Wg3,
    const float* __restrict__ Wg4, const float* __restrict__ Wg5,
    const float* __restrict__ Wg6, const float* __restrict__ Wg7,
    float* __restrict__ out) {
  __shared__ short lds_s[8 * 4608];
  __shared__ float cst[64 * 6];
  __shared__ int diagf;
  const int t = threadIdx.x;
  const int R0 = blockIdx.x * 64;
  const int lane = t & 63;
  const int wid = t >> 6;
  const int r0 = wid * 16;
  const int lg = lane >> 4;
  const int arow = r0 + (lane & 15);
  const f32x4 z = {0.f, 0.f, 0.f, 0.f};

  // ---- phase 0: stage x1 -> h/l planes; consts ----
  {
    if (t == 0) diagf = 0;
    int c = t;
    int plane_hi, u;
    if (c < 64) { plane_hi = 0; u = c; }
    else { int q = c - 64; u = q / 3; int m = q - u * 3; plane_hi = 2 + 2 * m; }
    short* phi = lds_s + plane_hi * 4608 + u;
    short* plo = phi + 4608;
    const float* xc = x1 + (size_t)R0 * 256 + c;
#pragma unroll 8
    for (int i = 0; i < 64; ++i) {
      short h, l;
      split2(xc[(size_t)i * 256], h, l);
      phi[i * 72] = h; plo[i * 72] = l;
    }
    if (t < 64) {
      f32x4 e = *(const f32x4*)(edge + (size_t)(R0 + t) * 4);
      float a = node[R0 + t];
      float* cr = cst + t * 6;
      cr[0] = e[0]; cr[1] = e[1]; cr[2] = e[2]; cr[3] = e[3];
      cr[4] = 0.125f * 0.08838834764831845f * a * a;
      cr[5] = 0.125f * a;
    }
  }
  __syncthreads();

  // ---- bit0: x1 staging readback via real ldpair path ----
  {
    int f = 0;
    const float* row = x1 + (size_t)(R0 + arow) * 256;
#pragma unroll
    for (int p = 0; p < 4; ++p) {
      bf16x8 ah[2], al[2];
      ldpair(lds_s, 2 * p, arow, lane, ah, al);
#pragma unroll
      for (int kh = 0; kh < 2; ++kh)
#pragma unroll
        for (int j = 0; j < 8; ++j) {
          int k = kh * 32 + lg * 8 + j;
          float r = bf2f(ah[kh][j]) + bf2f(al[kh][j]);
          float g = (p == 0) ? row[k] : row[64 + 3 * k + (p - 1)];
          if (fabsf(r - g) > 1e-3f * fabsf(g) + 1e-6f) f = 1;
        }
    }
    if (f) atomicOr(&diagf, 1);
  }
  // ---- bit1: cst readback ----
  if (t < 64) {
    int f = 0;
    f32x4 e = *(const f32x4*)(edge + (size_t)(R0 + t) * 4);
    float a = node[R0 + t];
    const float* cr = cst + t * 6;
    if (cr[0] != e[0] || cr[1] != e[1] || cr[2] != e[2] || cr[3] != e[3]) f = 1;
    if (fabsf(cr[4] - 0.125f * 0.08838834764831845f * a * a) > 1e-6f + 1e-5f * fabsf(cr[4])) f = 1;
    if (fabsf(cr[5] - 0.125f * a) > 1e-7f + 1e-5f * fabsf(cr[5])) f = 1;
    if (f) atomicOr(&diagf, 2);
  }
  // ---- bit2: ws readback at exact gemm3 addresses, all 8 mats ----
  {
    int f = 0;
    const float* Wgl[8] = {Wg0, Wg1, Wg2, Wg3, Wg4, Wg5, Wg6, Wg7};
#pragma unroll
    for (int mat = 0; mat < 8; ++mat) {
      const float* Wg = Wgl[mat];
      for (int ct = 0; ct < 4; ++ct)
        for (int kh = 0; kh < 2; ++kh) {
          const bf16x8 bh = *(const bf16x8*)(ws + ((size_t)(mat * 16) + ct * 2 + kh) * 512 + lane * 8);
          const bf16x8 bl = *(const bf16x8*)(ws + ((size_t)(mat * 16 + 8) + ct * 2 + kh) * 512 + lane * 8);
          int col = ct * 16 + (lane & 15);
          int k0 = kh * 32 + lg * 8;
#pragma unroll
          for (int j = 0; j < 8; ++j) {
            float r = bf2f(bh[j]) + bf2f(bl[j]);
            float g = Wg[(k0 + j) * 64 + col];
            if (fabsf(r - g) > 1e-3f * fabsf(g) + 1e-6f) f = 1;
          }
        }
    }
    if (f) atomicOr(&diagf, 4);
  }

  // ---- stage 1 MFMA ----
  f32x4 scs[4], s0v[4], scv[3][4], v0v[3][4];
  {
    bf16x8 ah[2], al[2];
    ldpair(lds_s, 0, arow, lane, ah, al);
#pragma unroll
    for (int ct = 0; ct < 4; ++ct) {
      scs[ct] = gemm3(ah, al, ws, 0, ct, lane, z);
      s0v[ct] = gemm3(ah, al, ws, 1, ct, lane, z);
    }
#pragma unroll
    for (int m = 0; m < 3; ++m) {
      ldpair(lds_s, 2 + 2 * m, arow, lane, ah, al);
#pragma unroll
      for (int ct = 0; ct < 4; ++ct) {
        scv[m][ct] = gemm3(ah, al, ws, 2, ct, lane, z);
        v0v[m][ct] = gemm3(ah, al, ws, 3, ct, lane, z);
      }
    }
  }

  // ---- bit3: stage-1 full check + REPLACE with f32 refs ----
  {
    int f = 0;
#pragma unroll
    for (int reg = 0; reg < 4; ++reg) {
      int n = r0 + (lg << 2) + reg;
      const float* xr = x1 + (size_t)(R0 + n) * 256;
#pragma unroll
      for (int ct = 0; ct < 4; ++ct) {
        int w = ct * 16 + (lane & 15);
        float r_scs = 0, r_s0 = 0, r_sv0 = 0, r_sv1 = 0, r_sv2 = 0, r_v0 = 0, r_v1 = 0, r_v2 = 0;
        for (int k = 0; k < 64; ++k) {
          float xs = xr[k];
          float xa = xr[64 + 3 * k], xb = xr[65 + 3 * k], xc2 = xr[66 + 3 * k];
          float w0 = Wg0[k * 64 + w], w1 = Wg1[k * 64 + w];
          float w2 = Wg2[k * 64 + w], w3 = Wg3[k * 64 + w];
          r_scs += xs * w0; r_s0 += xs * w1;
          r_sv0 += xa * w2; r_sv1 += xb * w2; r_sv2 += xc2 * w2;
          r_v0 += xa * w3; r_v1 += xb * w3; r_v2 += xc2 * w3;
        }
        if (CHK(scs[ct][reg], r_scs)) f = 1;  scs[ct][reg] = r_scs;
        if (CHK(s0v[ct][reg], r_s0)) f = 1;   s0v[ct][reg] = r_s0;
        if (CHK(scv[0][ct][reg], r_sv0)) f = 1; scv[0][ct][reg] = r_sv0;
        if (CHK(scv[1][ct][reg], r_sv1)) f = 1; scv[1][ct][reg] = r_sv1;
        if (CHK(scv[2][ct][reg], r_sv2)) f = 1; scv[2][ct][reg] = r_sv2;
        if (CHK(v0v[0][ct][reg], r_v0)) f = 1; v0v[0][ct][reg] = r_v0;
        if (CHK(v0v[1][ct][reg], r_v1)) f = 1; v0v[1][ct][reg] = r_v1;
        if (CHK(v0v[2][ct][reg], r_v2)) f = 1; v0v[2][ct][reg] = r_v2;
      }
    }
    if (f) atomicOr(&diagf, 8);
  }
  __syncthreads();

  // ---- phase 2a: mids (from REPLACED refs) -> planes 0-5 ----
#pragma unroll
  for (int reg = 0; reg < 4; ++reg) {
    int n = r0 + (lg << 2) + reg;
    const float* cr = cst + n * 6;
    float e0 = cr[0], e1x = cr[1], e1y = cr[2], e1z = cr[3];
    const float* tr = tp + (size_t)(R0 + n) * 256;
#pragma unroll
    for (int ct = 0; ct < 4; ++ct) {
      int w = ct * 16 + (lane & 15);
      float s0 = s0v[ct][reg];
      float vx = v0v[0][ct][reg], vy = v0v[1][ct][reg], vz = v0v[2][ct][reg];
      float mA = tr[w] * s0 * e0;
      float mB = tr[64 + w] * s0;
      float mD = tr[192 + w] * (vx * e1x + vy * e1y + vz * e1z) * 0.5773502691896258f;
      int off = n * 72 + w;
      short h, l;
      split2(mA, h, l); lds_s[off] = h;            lds_s[4608 + off] = l;
      split2(mB, h, l); lds_s[2 * 4608 + off] = h; lds_s[3 * 4608 + off] = l;
      split2(mD, h, l); lds_s[4 * 4608 + off] = h; lds_s[5 * 4608 + off] = l;
    }
  }
  __syncthreads();

  // ---- bit4: mid persistence ----
  {
    int f = 0;
#pragma unroll
    for (int reg = 0; reg < 4; ++reg) {
      int n = r0 + (lg << 2) + reg;
      const float* cr = cst + n * 6;
      const float* tr = tp + (size_t)(R0 + n) * 256;
#pragma unroll
      for (int ct = 0; ct < 4; ++ct) {
        int w = ct * 16 + (lane & 15);
        float mA = tr[w] * s0v[ct][reg] * cr[0];
        float mB = tr[64 + w] * s0v[ct][reg];
        float mD = tr[192 + w] * (v0v[0][ct][reg] * cr[1] + v0v[1][ct][reg] * cr[2] +
                                  v0v[2][ct][reg] * cr[3]) * 0.5773502691896258f;
        int off = n * 72 + w;
        float rA = bf2f(lds_s[off]) + bf2f(lds_s[4608 + off]);
        float rB = bf2f(lds_s[2 * 4608 + off]) + bf2f(lds_s[3 * 4608 + off]);
        float rD = bf2f(lds_s[4 * 4608 + off]) + bf2f(lds_s[5 * 4608 + off]);
        if (fabsf(rA - mA) > 2e-4f * fabsf(mA) + 2e-5f) f = 1;
        if (fabsf(rB - mB) > 2e-4f * fabsf(mB) + 2e-5f) f = 1;
        if (fabsf(rD - mD) > 2e-4f * fabsf(mD) + 2e-5f) f = 1;
      }
    }
    if (f) atomicOr(&diagf, 16);
  }

  // ---- stage 2a MFMA ----
  f32x4 gAD[4], gB[4];
  {
    bf16x8 ah[2], al[2];
    ldpair(lds_s, 0, arow, lane, ah, al);
#pragma unroll
    for (int ct = 0; ct < 4; ++ct) gAD[ct] = gemm3(ah, al, ws, 4, ct, lane, z);
    ldpair(lds_s, 4, arow, lane, ah, al);
#pragma unroll
    for (int ct = 0; ct < 4; ++ct) gAD[ct] = gemm3(ah, al, ws, 5, ct, lane, gAD[ct]);
    ldpair(lds_s, 2, arow, lane, ah, al);
#pragma unroll
    for (int ct = 0; ct < 4; ++ct) gB[ct] = gemm3(ah, al, ws, 6, ct, lane, z);
  }

  // ---- bit5: stage-2a check + REPLACE ----
  {
    int f = 0;
#pragma unroll
    for (int reg = 0; reg < 4; ++reg) {
      int n = r0 + (lg << 2) + reg;
#pragma unroll
      for (int ct = 0; ct < 4; ++ct) {
        int w = ct * 16 + (lane & 15);
        float rAD = 0.f, rB = 0.f;
        for (int u = 0; u < 64; ++u) {
          int off = n * 72 + u;
          float mA = bf2f(lds_s[off]) + bf2f(lds_s[4608 + off]);
          float mB = bf2f(lds_s[2 * 4608 + off]) + bf2f(lds_s[3 * 4608 + off]);
          float mD = bf2f(lds_s[4 * 4608 + off]) + bf2f(lds_s[5 * 4608 + off]);
          rAD += mA * Wg4[u * 64 + w] + mD * Wg5[u * 64 + w];
          rB += mB * Wg6[u * 64 + w];
        }
        if (CHK(gAD[ct][reg], rAD)) f = 1; gAD[ct][reg] = rAD;
        if (CHK(gB[ct][reg], rB)) f = 1;   gB[ct][reg] = rB;
      }
    }
    if (f) atomicOr(&diagf, 32);
  }
  __syncthreads();

  // ---- phase 2b: mC -> planes 0-5 ----
#pragma unroll
  for (int reg = 0; reg < 4; ++reg) {
    int n = r0 + (lg << 2) + reg;
    float e0 = cst[n * 6];
    const float* tr = tp + (size_t)(R0 + n) * 256;
#pragma unroll
    for (int ct = 0; ct < 4; ++ct) {
      int w = ct * 16 + (lane & 15);
      float wc = tr[128 + w];
      int off = n * 72 + w;
#pragma unroll
      for (int m = 0; m < 3; ++m) {
        short h, l;
        split2(wc * v0v[m][ct][reg] * e0, h, l);
        lds_s[(2 * m) * 4608 + off] = h;
        lds_s[(2 * m + 1) * 4608 + off] = l;
      }
    }
  }
  __syncthreads();

  // ---- stage 2b MFMA ----
  f32x4 gC[3][4];
  {
#pragma unroll
    for (int m = 0; m < 3; ++m) {
      bf16x8 ah[2], al[2];
      ldpair(lds_s, 2 * m, arow, lane, ah, al);
#pragma unroll
      for (int ct = 0; ct < 4; ++ct) gC[m][ct] = gemm3(ah, al, ws, 7, ct, lane, z);
    }
  }

  // ---- bit6: stage-2b check + REPLACE (all 3 components) ----
  {
    int f = 0;
#pragma unroll
    for (int reg = 0; reg < 4; ++reg) {
      int n = r0 + (lg << 2) + reg;
#pragma unroll
      for (int ct = 0; ct < 4; ++ct) {
        int w = ct * 16 + (lane & 15);
        float rC0 = 0.f, rC1 = 0.f, rC2 = 0.f;
        for (int u = 0; u < 64; ++u) {
          int off = n * 72 + u;
          float wcw = Wg7[u * 64 + w];
          rC0 += (bf2f(lds_s[off]) + bf2f(lds_s[4608 + off])) * wcw;
          rC1 += (bf2f(lds_s[2 * 4608 + off]) + bf2f(lds_s[3 * 4608 + off])) * wcw;
          rC2 += (bf2f(lds_s[4 * 4608 + off]) + bf2f(lds_s[5 * 4608 + off])) * wcw;
        }
        if (CHK(gC[0][ct][reg], rC0)) f = 1; gC[0][ct][reg] = rC0;
        if (CHK(gC[1][ct][reg], rC1)) f = 1; gC[1][ct][reg] = rC1;
        if (CHK(gC[2][ct][reg], rC2)) f = 1; gC[2][ct][reg] = rC2;
      }
    }
    if (f) atomicOr(&diagf, 64);
  }

  // ---- epilogue ----
#pragma unroll
  for (int reg = 0; reg < 4; ++reg) {
    int n = r0 + (lg << 2) + reg;
    const float* cr = cst + n * 6;
    float e1x = cr[1], e1y = cr[2], e1z = cr[3], kp = cr[4], ksc = cr[5];
    float* orow = out + (size_t)(R0 + n) * 256;
#pragma unroll
    for (int ct = 0; ct < 4; ++ct) {
      int w = ct * 16 + (lane & 15);
      orow[w] = kp * gAD[ct][reg] + ksc * scs[ct][reg];
      float vx = kp * (e1x * gB[ct][reg] + gC[0][ct][reg]) + ksc * scv[0][ct][reg];
      float vy = kp * (e1y * gB[ct][reg] + gC[1][ct][reg]) + ksc * scv[1][ct][reg];
      float vz = kp * (e1z * gB[ct][reg] + gC[2][ct][reg]) + ksc * scv[2][ct][reg];
      float* vp = orow + 64 + 3 * w;
      vp[0] = vx; vp[1] = vy; vp[2] = vz;
    }
  }

  // ---- diag stamp: own-block cell, ordered after own epilogue ----
  __syncthreads();
  if (t == 0 && diagf) {
    out[(size_t)R0 * 256] = 8192.0f + 256.0f * (float)diagf;
  }
}

extern "C" void kernel_launch(void* const* d_in, const int* in_sizes, int n_in,
                              void* d_out, int out_size, void* d_ws, size_t ws_size,
                              hipStream_t stream) {
  const float* x1   = (const float*)d_in[0];
  const float* edge = (const float*)d_in[1];
  const float* tp   = (const float*)d_in[2];
  const float* node = (const float*)d_in[3];
  short* ws = (short*)d_ws;
  int n = in_sizes[0] / 256;

  prep_w<<<16, 256, 0, stream>>>(
      (const float*)d_in[6], (const float*)d_in[4],
      (const float*)d_in[7], (const float*)d_in[5],
      (const float*)d_in[8], (const float*)d_in[9],
      (const float*)d_in[10], (const float*)d_in[11], ws);

  fused_tp<<<n / 64, 256, 0, stream>>>(
      x1, edge, tp, node, ws,
      (const float*)d_in[6],  // Wg0 = W_sc_s
      (const float*)d_in[4],  // Wg1 = W_lin0_s
      (const float*)d_in[7],  // Wg2 = W_sc_v
      (const float*)d_in[5],  // Wg3 = W_lin0_v
      (const float*)d_in[8],  // Wg4 = W_lin_A
      (const float*)d_in[9],  // Wg5 = W_lin_D
      (const float*)d_in[10], // Wg6 = W_lin_B
      (const float*)d_in[11], // Wg7 = W_lin_C
      (float*)d_out);
}

// Round 11
// 564.784 us; speedup vs baseline: 3.5842x; 3.5842x over previous
//
#include <hip/hip_runtime.h>

typedef __attribute__((ext_vector_type(4))) float f32x4;

// Pure-f32 VALU pipeline (R4/R6-proven algebra), restructured for speed:
//  - 512 threads (8 waves), 32 rows/block; thread (w=t&63, g=t>>6) owns rows g*4+i, col w
//  - stage-1 outputs stay in registers (ownership identical across stages; mids wave-private)
//  - 4 LDS planes [32][64] f32, reused: {s,vx,vy,vz} -> {mA,mB,mD} -> {mCx,mCy,mCz}
//  - tp prefetched in phase A (HBM latency hidden under stage-1)
//  - fused inner loops: one A-plane read feeds all mats sharing that operand
__global__ __launch_bounds__(512, 4) void fused_f32(
    const float* __restrict__ x1, const float* __restrict__ edge,
    const float* __restrict__ tp, const float* __restrict__ node,
    const float* __restrict__ Wsc_s, const float* __restrict__ Wlin0_s,
    const float* __restrict__ Wsc_v, const float* __restrict__ Wlin0_v,
    const float* __restrict__ WA, const float* __restrict__ WD,
    const float* __restrict__ WB, const float* __restrict__ WC,
    float* __restrict__ out) {
  __shared__ float P[4][32][64];
  __shared__ float cst[32][6];
  const int t = threadIdx.x;
  const int R0 = blockIdx.x * 32;
  const int w = t & 63;
  const int g = t >> 6;  // wave id == row-group: rows g*4 .. g*4+3

  // ---- phase A: prefetch tp; stage x1 via f32x4; consts ----
  float wa[4], wb[4], wcc[4], wd[4];
#pragma unroll
  for (int i = 0; i < 4; ++i) {
    const float* tr = tp + (size_t)(R0 + g * 4 + i) * 256;
    wa[i] = tr[w]; wb[i] = tr[64 + w]; wcc[i] = tr[128 + w]; wd[i] = tr[192 + w];
  }
#pragma unroll
  for (int k = 0; k < 4; ++k) {
    int vi = t + k * 512;            // 2048 f32x4 = 32 rows x 256 cols
    int r = vi >> 6;
    int c4 = (vi & 63) * 4;
    f32x4 v = *(const f32x4*)(x1 + (size_t)(R0 + r) * 256 + c4);
#pragma unroll
    for (int j = 0; j < 4; ++j) {
      int c = c4 + j;
      if (c < 64) P[0][r][c] = v[j];
      else { int q = c - 64; int u = q / 3; int m = q - 3 * u; P[1 + m][r][u] = v[j]; }
    }
  }
  if (t < 32) {
    f32x4 e = *(const f32x4*)(edge + (size_t)(R0 + t) * 4);
    float a = node[R0 + t];
    cst[t][0] = e[0]; cst[t][1] = e[1]; cst[t][2] = e[2]; cst[t][3] = e[3];
    cst[t][4] = 0.125f * 0.08838834764831845f * a * a;  // kp
    cst[t][5] = 0.125f * a;                             // ksc
  }
  __syncthreads();

  const f32x4 z4 = {0.f, 0.f, 0.f, 0.f};

  // ---- stage 1 (fused): scs,s0r from P0; (scv,v0r)[m] from P1..P3 ----
  f32x4 scs = z4, s0r = z4;
  f32x4 scv0 = z4, scv1 = z4, scv2 = z4;
  f32x4 v0r0 = z4, v0r1 = z4, v0r2 = z4;
#pragma unroll 2
  for (int uc = 0; uc < 16; ++uc) {
    int u0 = uc * 4;
    f32x4 wss, wl0s, wsv, wl0v;
#pragma unroll
    for (int j = 0; j < 4; ++j) {
      int o = (u0 + j) * 64 + w;
      wss[j] = Wsc_s[o]; wl0s[j] = Wlin0_s[o]; wsv[j] = Wsc_v[o]; wl0v[j] = Wlin0_v[o];
    }
#pragma unroll
    for (int i = 0; i < 4; ++i) {
      f32x4 xs = *(const f32x4*)(&P[0][g * 4 + i][u0]);
#pragma unroll
      for (int j = 0; j < 4; ++j) { scs[i] += xs[j] * wss[j]; s0r[i] += xs[j] * wl0s[j]; }
    }
#pragma unroll
    for (int i = 0; i < 4; ++i) {
      f32x4 xv = *(const f32x4*)(&P[1][g * 4 + i][u0]);
#pragma unroll
      for (int j = 0; j < 4; ++j) { scv0[i] += xv[j] * wsv[j]; v0r0[i] += xv[j] * wl0v[j]; }
    }
#pragma unroll
    for (int i = 0; i < 4; ++i) {
      f32x4 xv = *(const f32x4*)(&P[2][g * 4 + i][u0]);
#pragma unroll
      for (int j = 0; j < 4; ++j) { scv1[i] += xv[j] * wsv[j]; v0r1[i] += xv[j] * wl0v[j]; }
    }
#pragma unroll
    for (int i = 0; i < 4; ++i) {
      f32x4 xv = *(const f32x4*)(&P[3][g * 4 + i][u0]);
#pragma unroll
      for (int j = 0; j < 4; ++j) { scv2[i] += xv[j] * wsv[j]; v0r2[i] += xv[j] * wl0v[j]; }
    }
  }
  __syncthreads();

  // ---- phase C: mids mA->P0, mB->P1, mD->P2 (wave-private rows) ----
#pragma unroll
  for (int i = 0; i < 4; ++i) {
    int n = g * 4 + i;
    float e0 = cst[n][0], e1x = cst[n][1], e1y = cst[n][2], e1z = cst[n][3];
    float s0 = s0r[i];
    float dot = v0r0[i] * e1x + v0r1[i] * e1y + v0r2[i] * e1z;
    P[0][n][w] = wa[i] * s0 * e0;
    P[1][n][w] = wb[i] * s0;
    P[2][n][w] = wd[i] * dot * 0.5773502691896258f;
  }
  __syncthreads();

  // ---- stage 2a (fused): gAD = mA@WA + mD@WD ; gB = mB@WB ----
  f32x4 gAD = z4, gB = z4;
#pragma unroll 2
  for (int uc = 0; uc < 16; ++uc) {
    int u0 = uc * 4;
    f32x4 wA_, wD_, wB_;
#pragma unroll
    for (int j = 0; j < 4; ++j) {
      int o = (u0 + j) * 64 + w;
      wA_[j] = WA[o]; wD_[j] = WD[o]; wB_[j] = WB[o];
    }
#pragma unroll
    for (int i = 0; i < 4; ++i) {
      f32x4 ma = *(const f32x4*)(&P[0][g * 4 + i][u0]);
      f32x4 mb = *(const f32x4*)(&P[1][g * 4 + i][u0]);
      f32x4 md = *(const f32x4*)(&P[2][g * 4 + i][u0]);
#pragma unroll
      for (int j = 0; j < 4; ++j) {
        gAD[i] += ma[j] * wA_[j] + md[j] * wD_[j];
        gB[i] += mb[j] * wB_[j];
      }
    }
  }
  __syncthreads();

  // ---- phase E: mC_m -> P0..P2 (reuse) ----
#pragma unroll
  for (int i = 0; i < 4; ++i) {
    int n = g * 4 + i;
    float e0 = cst[n][0];
    float wc = wcc[i];
    P[0][n][w] = wc * v0r0[i] * e0;
    P[1][n][w] = wc * v0r1[i] * e0;
    P[2][n][w] = wc * v0r2[i] * e0;
  }
  __syncthreads();

  // ---- stage 2b (fused): gC_m = mC_m @ WC ----
  f32x4 gC0 = z4, gC1 = z4, gC2 = z4;
#pragma unroll 2
  for (int uc = 0; uc < 16; ++uc) {
    int u0 = uc * 4;
    f32x4 wC_;
#pragma unroll
    for (int j = 0; j < 4; ++j) wC_[j] = WC[(u0 + j) * 64 + w];
#pragma unroll
    for (int i = 0; i < 4; ++i) {
      f32x4 m0 = *(const f32x4*)(&P[0][g * 4 + i][u0]);
      f32x4 m1 = *(const f32x4*)(&P[1][g * 4 + i][u0]);
      f32x4 m2 = *(const f32x4*)(&P[2][g * 4 + i][u0]);
#pragma unroll
      for (int j = 0; j < 4; ++j) {
        gC0[i] += m0[j] * wC_[j];
        gC1[i] += m1[j] * wC_[j];
        gC2[i] += m2[j] * wC_[j];
      }
    }
  }

  // ---- epilogue (R4-proven) ----
#pragma unroll
  for (int i = 0; i < 4; ++i) {
    int n = g * 4 + i;
    float e1x = cst[n][1], e1y = cst[n][2], e1z = cst[n][3];
    float kp = cst[n][4], ksc = cst[n][5];
    float* orow = out + (size_t)(R0 + n) * 256;
    orow[w] = kp * gAD[i] + ksc * scs[i];
    float vx = kp * (e1x * gB[i] + gC0[i]) + ksc * scv0[i];
    float vy = kp * (e1y * gB[i] + gC1[i]) + ksc * scv1[i];
    float vz = kp * (e1z * gB[i] + gC2[i]) + ksc * scv2[i];
    float* vp = orow + 64 + 3 * w;
    vp[0] = vx; vp[1] = vy; vp[2] = vz;
  }
}

extern "C" void kernel_launch(void* const* d_in, const int* in_sizes, int n_in,
                              void* d_out, int out_size, void* d_ws, size_t ws_size,
                              hipStream_t stream) {
  const float* x1   = (const float*)d_in[0];
  const float* edge = (const float*)d_in[1];
  const float* tp   = (const float*)d_in[2];
  const float* node = (const float*)d_in[3];
  int n = in_sizes[0] / 256;  // 200000

  fused_f32<<<n / 32, 512, 0, stream>>>(
      x1, edge, tp, node,
      (const float*)d_in[6],  // W_sc_s
      (const float*)d_in[4],  // W_lin0_s
      (const float*)d_in[7],  // W_sc_v
      (const float*)d_in[5],  // W_lin0_v
      (const float*)d_in[8],  // W_lin_A
      (const float*)d_in[9],  // W_lin_D
      (const float*)d_in[10], // W_lin_B
      (const float*)d_in[11], // W_lin_C
      (float*)d_out);
}

// Round 12
// 529.045 us; speedup vs baseline: 3.8263x; 1.0676x over previous
//
#include <hip/hip_runtime.h>

typedef __attribute__((ext_vector_type(4))) float f32x4;

// Pure-f32 VALU pipeline (R4/R6-proven algebra).
// R12: 256 threads (4 waves), 32 rows/block, 8 rows/thread (halves weight-load
// overhead per FMA vs R11), launch_bounds(256,3) for ~170 VGPRs (R11's 64-VGPR
// cap forced rematerialization).
__global__ __launch_bounds__(256, 3) void fused_f32(
    const float* __restrict__ x1, const float* __restrict__ edge,
    const float* __restrict__ tp, const float* __restrict__ node,
    const float* __restrict__ Wsc_s, const float* __restrict__ Wlin0_s,
    const float* __restrict__ Wsc_v, const float* __restrict__ Wlin0_v,
    const float* __restrict__ WA, const float* __restrict__ WD,
    const float* __restrict__ WB, const float* __restrict__ WC,
    float* __restrict__ out) {
  __shared__ float P[4][32][64];
  __shared__ float cst[32][6];
  const int t = threadIdx.x;
  const int R0 = blockIdx.x * 32;
  const int w = t & 63;
  const int g = t >> 6;  // wave id: rows g*8 .. g*8+7

  // ---- phase A: prefetch tp (8 rows); stage x1 via f32x4; consts ----
  float wa[8], wb[8], wcc[8], wd[8];
#pragma unroll
  for (int i = 0; i < 8; ++i) {
    const float* tr = tp + (size_t)(R0 + g * 8 + i) * 256;
    wa[i] = tr[w]; wb[i] = tr[64 + w]; wcc[i] = tr[128 + w]; wd[i] = tr[192 + w];
  }
#pragma unroll
  for (int k = 0; k < 8; ++k) {
    int vi = t + k * 256;            // 2048 f32x4 = 32 rows x 256 cols
    int r = vi >> 6;
    int c4 = (vi & 63) * 4;
    f32x4 v = *(const f32x4*)(x1 + (size_t)(R0 + r) * 256 + c4);
#pragma unroll
    for (int j = 0; j < 4; ++j) {
      int c = c4 + j;
      if (c < 64) P[0][r][c] = v[j];
      else { int q = c - 64; int u = q / 3; int m = q - 3 * u; P[1 + m][r][u] = v[j]; }
    }
  }
  if (t < 32) {
    f32x4 e = *(const f32x4*)(edge + (size_t)(R0 + t) * 4);
    float a = node[R0 + t];
    cst[t][0] = e[0]; cst[t][1] = e[1]; cst[t][2] = e[2]; cst[t][3] = e[3];
    cst[t][4] = 0.125f * 0.08838834764831845f * a * a;  // kp
    cst[t][5] = 0.125f * a;                             // ksc
  }
  __syncthreads();

  // ---- stage 1 (fused): 8 accumulators x 8 rows ----
  float scs[8] = {0,0,0,0,0,0,0,0}, s0r[8] = {0,0,0,0,0,0,0,0};
  float scv0[8] = {0,0,0,0,0,0,0,0}, scv1[8] = {0,0,0,0,0,0,0,0}, scv2[8] = {0,0,0,0,0,0,0,0};
  float v0r0[8] = {0,0,0,0,0,0,0,0}, v0r1[8] = {0,0,0,0,0,0,0,0}, v0r2[8] = {0,0,0,0,0,0,0,0};
  for (int uc = 0; uc < 16; ++uc) {
    int u0 = uc * 4;
    f32x4 wss, wl0s, wsv, wl0v;
#pragma unroll
    for (int j = 0; j < 4; ++j) {
      int o = (u0 + j) * 64 + w;
      wss[j] = Wsc_s[o]; wl0s[j] = Wlin0_s[o]; wsv[j] = Wsc_v[o]; wl0v[j] = Wlin0_v[o];
    }
#pragma unroll
    for (int i = 0; i < 8; ++i) {
      f32x4 xs = *(const f32x4*)(&P[0][g * 8 + i][u0]);
#pragma unroll
      for (int j = 0; j < 4; ++j) { scs[i] += xs[j] * wss[j]; s0r[i] += xs[j] * wl0s[j]; }
    }
#pragma unroll
    for (int i = 0; i < 8; ++i) {
      f32x4 xv = *(const f32x4*)(&P[1][g * 8 + i][u0]);
#pragma unroll
      for (int j = 0; j < 4; ++j) { scv0[i] += xv[j] * wsv[j]; v0r0[i] += xv[j] * wl0v[j]; }
    }
#pragma unroll
    for (int i = 0; i < 8; ++i) {
      f32x4 xv = *(const f32x4*)(&P[2][g * 8 + i][u0]);
#pragma unroll
      for (int j = 0; j < 4; ++j) { scv1[i] += xv[j] * wsv[j]; v0r1[i] += xv[j] * wl0v[j]; }
    }
#pragma unroll
    for (int i = 0; i < 8; ++i) {
      f32x4 xv = *(const f32x4*)(&P[3][g * 8 + i][u0]);
#pragma unroll
      for (int j = 0; j < 4; ++j) { scv2[i] += xv[j] * wsv[j]; v0r2[i] += xv[j] * wl0v[j]; }
    }
  }
  __syncthreads();

  // ---- phase C: mids mA->P0, mB->P1, mD->P2 (wave-private rows) ----
#pragma unroll
  for (int i = 0; i < 8; ++i) {
    int n = g * 8 + i;
    float e0 = cst[n][0], e1x = cst[n][1], e1y = cst[n][2], e1z = cst[n][3];
    float s0 = s0r[i];
    float dot = v0r0[i] * e1x + v0r1[i] * e1y + v0r2[i] * e1z;
    P[0][n][w] = wa[i] * s0 * e0;
    P[1][n][w] = wb[i] * s0;
    P[2][n][w] = wd[i] * dot * 0.5773502691896258f;
  }
  __syncthreads();

  // ---- stage 2a (fused): gAD = mA@WA + mD@WD ; gB = mB@WB ----
  float gAD[8] = {0,0,0,0,0,0,0,0}, gB[8] = {0,0,0,0,0,0,0,0};
  for (int uc = 0; uc < 16; ++uc) {
    int u0 = uc * 4;
    f32x4 wA_, wD_, wB_;
#pragma unroll
    for (int j = 0; j < 4; ++j) {
      int o = (u0 + j) * 64 + w;
      wA_[j] = WA[o]; wD_[j] = WD[o]; wB_[j] = WB[o];
    }
#pragma unroll
    for (int i = 0; i < 8; ++i) {
      f32x4 ma = *(const f32x4*)(&P[0][g * 8 + i][u0]);
      f32x4 mb = *(const f32x4*)(&P[1][g * 8 + i][u0]);
      f32x4 md = *(const f32x4*)(&P[2][g * 8 + i][u0]);
#pragma unroll
      for (int j = 0; j < 4; ++j) {
        gAD[i] += ma[j] * wA_[j] + md[j] * wD_[j];
        gB[i] += mb[j] * wB_[j];
      }
    }
  }
  __syncthreads();

  // ---- phase E: mC_m -> P0..P2 (reuse) ----
#pragma unroll
  for (int i = 0; i < 8; ++i) {
    int n = g * 8 + i;
    float e0 = cst[n][0];
    float wc = wcc[i];
    P[0][n][w] = wc * v0r0[i] * e0;
    P[1][n][w] = wc * v0r1[i] * e0;
    P[2][n][w] = wc * v0r2[i] * e0;
  }
  __syncthreads();

  // ---- stage 2b (fused): gC_m = mC_m @ WC ----
  float gC0[8] = {0,0,0,0,0,0,0,0}, gC1[8] = {0,0,0,0,0,0,0,0}, gC2[8] = {0,0,0,0,0,0,0,0};
  for (int uc = 0; uc < 16; ++uc) {
    int u0 = uc * 4;
    f32x4 wC_;
#pragma unroll
    for (int j = 0; j < 4; ++j) wC_[j] = WC[(u0 + j) * 64 + w];
#pragma unroll
    for (int i = 0; i < 8; ++i) {
      f32x4 m0 = *(const f32x4*)(&P[0][g * 8 + i][u0]);
      f32x4 m1 = *(const f32x4*)(&P[1][g * 8 + i][u0]);
      f32x4 m2 = *(const f32x4*)(&P[2][g * 8 + i][u0]);
#pragma unroll
      for (int j = 0; j < 4; ++j) {
        gC0[i] += m0[j] * wC_[j];
        gC1[i] += m1[j] * wC_[j];
        gC2[i] += m2[j] * wC_[j];
      }
    }
  }

  // ---- epilogue (R4-proven) ----
#pragma unroll
  for (int i = 0; i < 8; ++i) {
    int n = g * 8 + i;
    float e1x = cst[n][1], e1y = cst[n][2], e1z = cst[n][3];
    float kp = cst[n][4], ksc = cst[n][5];
    float* orow = out + (size_t)(R0 + n) * 256;
    orow[w] = kp * gAD[i] + ksc * scs[i];
    float vx = kp * (e1x * gB[i] + gC0[i]) + ksc * scv0[i];
    float vy = kp * (e1y * gB[i] + gC1[i]) + ksc * scv1[i];
    float vz = kp * (e1z * gB[i] + gC2[i]) + ksc * scv2[i];
    float* vp = orow + 64 + 3 * w;
    vp[0] = vx; vp[1] = vy; vp[2] = vz;
  }
}

extern "C" void kernel_launch(void* const* d_in, const int* in_sizes, int n_in,
                              void* d_out, int out_size, void* d_ws, size_t ws_size,
                              hipStream_t stream) {
  const float* x1   = (const float*)d_in[0];
  const float* edge = (const float*)d_in[1];
  const float* tp   = (const float*)d_in[2];
  const float* node = (const float*)d_in[3];
  int n = in_sizes[0] / 256;  // 200000

  fused_f32<<<n / 32, 256, 0, stream>>>(
      x1, edge, tp, node,
      (const float*)d_in[6],  // W_sc_s
      (const float*)d_in[4],  // W_lin0_s
      (const float*)d_in[7],  // W_sc_v
      (const float*)d_in[5],  // W_lin0_v
      (const float*)d_in[8],  // W_lin_A
      (const float*)d_in[9],  // W_lin_D
      (const float*)d_in[10], // W_lin_B
      (const float*)d_in[11], // W_lin_C
      (float*)d_out);
}

// Round 13
// 180.762 us; speedup vs baseline: 11.1986x; 2.9268x over previous
//
#include <hip/hip_runtime.h>

typedef __attribute__((ext_vector_type(4))) float f32x4;
typedef __attribute__((ext_vector_type(8))) short bf16x8;

#define MFMA(a, b, c) __builtin_amdgcn_mfma_f32_16x16x32_bf16(a, b, c, 0, 0, 0)
// WAR-hazard shield: no instruction may be scheduled into/across the cluster,
// and 32 idle cycles ensure no async load writeback lands on MFMA source regs.
#define NOPS asm volatile("s_nop 7\ns_nop 7\ns_nop 7\ns_nop 7" ::: "memory")

// split f32 -> hi (trunc bf16) + lo (RNE bf16 of residual)
static __device__ __forceinline__ void split2(float x, short& hi, short& lo) {
  union { float f; unsigned u; } v; v.f = x;
  unsigned uh = v.u & 0xFFFF0000u;
  hi = (short)(uh >> 16);
  union { unsigned u; float f; } w; w.u = uh;
  union { float f; unsigned u; } z; z.f = x - w.f;  // exact
  lo = (short)((z.u + 0x7FFFu + ((z.u >> 16) & 1u)) >> 16);  // RNE
}

// ---------------- prep: pack 8 weights as hi/lo B-fragments (R8-identical) ----------------
__global__ void prep_w(const float* __restrict__ W0, const float* __restrict__ W1,
                       const float* __restrict__ W2, const float* __restrict__ W3,
                       const float* __restrict__ W4, const float* __restrict__ W5,
                       const float* __restrict__ W6, const float* __restrict__ W7,
                       short* __restrict__ ws) {
  const float* W[8] = {W0, W1, W2, W3, W4, W5, W6, W7};
  int t = blockIdx.x * 256 + threadIdx.x;
  int lane = t & 63, fragid = (t >> 6) & 7, mat = t >> 9;
  const float* Wm = W[mat];
  int ct = fragid >> 1, kh = fragid & 1;
  int wcol = ct * 16 + (lane & 15);
  int k0 = kh * 32 + ((lane >> 4) << 3);
  bf16x8 vh, vl;
#pragma unroll
  for (int j = 0; j < 8; ++j) {
    short h, l;
    split2(Wm[(k0 + j) * 64 + wcol], h, l);
    vh[j] = h; vl[j] = l;
  }
  size_t base = ((size_t)(mat * 16) + fragid) * 512 + lane * 8;
  *(bf16x8*)(ws + base) = vh;
  *(bf16x8*)(ws + base + 4096) = vl;
}

struct BF { bf16x8 h[4][2], l[4][2]; };

// preload ALL B-fragments of one matrix into dedicated registers
static __device__ __forceinline__ void loadB(const short* __restrict__ ws, int mat, int lane,
                                             BF& B) {
#pragma unroll
  for (int ct = 0; ct < 4; ++ct)
#pragma unroll
    for (int kh = 0; kh < 2; ++kh) {
      B.h[ct][kh] = *(const bf16x8*)(ws + ((size_t)(mat * 16) + ct * 2 + kh) * 512 + lane * 8);
      B.l[ct][kh] = *(const bf16x8*)(ws + ((size_t)(mat * 16 + 8) + ct * 2 + kh) * 512 + lane * 8);
    }
}

// fenced MFMA cluster: 24 MFMAs, no loads inside, hazard nops after
static __device__ __forceinline__ void cluster(const bf16x8 (&ah)[2], const bf16x8 (&al)[2],
                                               const BF& B, f32x4 (&acc)[4]) {
  __builtin_amdgcn_sched_barrier(0);
#pragma unroll
  for (int ct = 0; ct < 4; ++ct)
#pragma unroll
    for (int kh = 0; kh < 2; ++kh) {
      acc[ct] = MFMA(ah[kh], B.h[ct][kh], acc[ct]);
      acc[ct] = MFMA(al[kh], B.h[ct][kh], acc[ct]);
      acc[ct] = MFMA(ah[kh], B.l[ct][kh], acc[ct]);
    }
  __builtin_amdgcn_sched_barrier(0);
  NOPS;
}

// A-frag hi/lo pair from padded LDS planes (stride 72 shorts, plane 4608 shorts)
static __device__ __forceinline__ void ldpair(const short* lds_s, int plane_hi, int arow, int lane,
                                              bf16x8 (&ah)[2], bf16x8 (&al)[2]) {
#pragma unroll
  for (int kh = 0; kh < 2; ++kh) {
    int off = arow * 72 + kh * 32 + ((lane >> 4) << 3);
    ah[kh] = *(const bf16x8*)(lds_s + plane_hi * 4608 + off);
    al[kh] = *(const bf16x8*)(lds_s + (plane_hi + 1) * 4608 + off);
  }
}

// ---------------- fused kernel: 64 rows/block, 256 threads (R8 dataflow) ----------------
__global__ __launch_bounds__(256, 2) void fused_tp(
    const float* __restrict__ x1, const float* __restrict__ edge,
    const float* __restrict__ tp, const float* __restrict__ node,
    const short* __restrict__ ws, float* __restrict__ out) {
  __shared__ short lds_s[8 * 4608];
  __shared__ float cst[64 * 6];
  const int t = threadIdx.x;
  const int R0 = blockIdx.x * 64;

  // ---- phase 0: stage x1 -> h/l planes (col-per-thread); consts ----
  {
    int c = t;
    int plane_hi, u;
    if (c < 64) { plane_hi = 0; u = c; }
    else { int q = c - 64; u = q / 3; int m = q - u * 3; plane_hi = 2 + 2 * m; }
    short* phi = lds_s + plane_hi * 4608 + u;
    short* plo = phi + 4608;
    const float* xc = x1 + (size_t)R0 * 256 + c;
#pragma unroll 8
    for (int i = 0; i < 64; ++i) {
      short h, l;
      split2(xc[(size_t)i * 256], h, l);
      phi[i * 72] = h; plo[i * 72] = l;
    }
    if (t < 64) {
      f32x4 e = *(const f32x4*)(edge + (size_t)(R0 + t) * 4);
      float a = node[R0 + t];
      float* cr = cst + t * 6;
      cr[0] = e[0]; cr[1] = e[1]; cr[2] = e[2]; cr[3] = e[3];
      cr[4] = 0.125f * 0.08838834764831845f * a * a;  // kp
      cr[5] = 0.125f * a;                             // ksc
    }
  }
  __syncthreads();

  const int lane = t & 63;
  const int wid = t >> 6;
  const int r0 = wid * 16;
  const int lg = lane >> 4;
  const int arow = r0 + (lane & 15);
  const f32x4 z = {0.f, 0.f, 0.f, 0.f};

  // ---- stage 1: 8 GEMMs via fenced clusters ----
  f32x4 scs[4], s0v[4], scv[3][4], v0v[3][4];
#pragma unroll
  for (int ct = 0; ct < 4; ++ct) { scs[ct] = z; s0v[ct] = z; }
#pragma unroll
  for (int m = 0; m < 3; ++m)
#pragma unroll
    for (int ct = 0; ct < 4; ++ct) { scv[m][ct] = z; v0v[m][ct] = z; }
  {
    BF B;
    bf16x8 ah[2], al[2];
    ldpair(lds_s, 0, arow, lane, ah, al);          // s
    loadB(ws, 0, lane, B); cluster(ah, al, B, scs);   // W_sc_s
    loadB(ws, 1, lane, B); cluster(ah, al, B, s0v);   // W_lin0_s
    loadB(ws, 2, lane, B);                            // W_sc_v
#pragma unroll
    for (int m = 0; m < 3; ++m) {
      ldpair(lds_s, 2 + 2 * m, arow, lane, ah, al);
      cluster(ah, al, B, scv[m]);
    }
    loadB(ws, 3, lane, B);                            // W_lin0_v
#pragma unroll
    for (int m = 0; m < 3; ++m) {
      ldpair(lds_s, 2 + 2 * m, arow, lane, ah, al);
      cluster(ah, al, B, v0v[m]);
    }
  }
  __syncthreads();

  // ---- phase 2a: mids mA->(0,1) mB->(2,3) mD->(4,5) ----
#pragma unroll
  for (int reg = 0; reg < 4; ++reg) {
    int n = r0 + (lg << 2) + reg;
    const float* cr = cst + n * 6;
    float e0 = cr[0], e1x = cr[1], e1y = cr[2], e1z = cr[3];
    const float* tr = tp + (size_t)(R0 + n) * 256;
#pragma unroll
    for (int ct = 0; ct < 4; ++ct) {
      int w = ct * 16 + (lane & 15);
      float s0 = s0v[ct][reg];
      float dot = v0v[0][ct][reg] * e1x + v0v[1][ct][reg] * e1y + v0v[2][ct][reg] * e1z;
      int off = n * 72 + w;
      short h, l;
      split2(tr[w] * s0 * e0, h, l);      lds_s[off] = h;            lds_s[4608 + off] = l;
      split2(tr[64 + w] * s0, h, l);      lds_s[2 * 4608 + off] = h; lds_s[3 * 4608 + off] = l;
      split2(tr[192 + w] * dot * 0.5773502691896258f, h, l);
                                          lds_s[4 * 4608 + off] = h; lds_s[5 * 4608 + off] = l;
    }
  }
  __syncthreads();

  // ---- stage 2a: gAD = mA@W_A + mD@W_D ; gB = mB@W_B ----
  f32x4 gAD[4], gB[4];
#pragma unroll
  for (int ct = 0; ct < 4; ++ct) { gAD[ct] = z; gB[ct] = z; }
  {
    BF B;
    bf16x8 ah[2], al[2];
    loadB(ws, 4, lane, B);                 // W_lin_A
    ldpair(lds_s, 0, arow, lane, ah, al);  // mA
    cluster(ah, al, B, gAD);
    loadB(ws, 5, lane, B);                 // W_lin_D
    ldpair(lds_s, 4, arow, lane, ah, al);  // mD
    cluster(ah, al, B, gAD);
    loadB(ws, 6, lane, B);                 // W_lin_B
    ldpair(lds_s, 2, arow, lane, ah, al);  // mB
    cluster(ah, al, B, gB);
  }

  // ---- early s-channel store (frees scs/gAD) ----
#pragma unroll
  for (int reg = 0; reg < 4; ++reg) {
    int n = r0 + (lg << 2) + reg;
    const float* cr = cst + n * 6;
    float kp = cr[4], ksc = cr[5];
    float* orow = out + (size_t)(R0 + n) * 256;
#pragma unroll
    for (int ct = 0; ct < 4; ++ct) {
      int w = ct * 16 + (lane & 15);
      orow[w] = kp * gAD[ct][reg] + ksc * scs[ct][reg];
    }
  }
  __syncthreads();

  // ---- phase 2b: mC x->(0,1) y->(2,3) z->(4,5) ----
#pragma unroll
  for (int reg = 0; reg < 4; ++reg) {
    int n = r0 + (lg << 2) + reg;
    float e0 = cst[n * 6];
    const float* tr = tp + (size_t)(R0 + n) * 256;
#pragma unroll
    for (int ct = 0; ct < 4; ++ct) {
      int w = ct * 16 + (lane & 15);
      float wc = tr[128 + w];
      int off = n * 72 + w;
#pragma unroll
      for (int m = 0; m < 3; ++m) {
        short h, l;
        split2(wc * v0v[m][ct][reg] * e0, h, l);
        lds_s[(2 * m) * 4608 + off] = h;
        lds_s[(2 * m + 1) * 4608 + off] = l;
      }
    }
  }
  __syncthreads();

  // ---- stage 2b: gC_m = mC_m @ W_C ----
  f32x4 gC[3][4];
#pragma unroll
  for (int m = 0; m < 3; ++m)
#pragma unroll
    for (int ct = 0; ct < 4; ++ct) gC[m][ct] = z;
  {
    BF B;
    loadB(ws, 7, lane, B);                 // W_lin_C
#pragma unroll
    for (int m = 0; m < 3; ++m) {
      bf16x8 ah[2], al[2];
      ldpair(lds_s, 2 * m, arow, lane, ah, al);
      cluster(ah, al, B, gC[m]);
    }
  }

  // ---- epilogue: v-channels ----
#pragma unroll
  for (int reg = 0; reg < 4; ++reg) {
    int n = r0 + (lg << 2) + reg;
    const float* cr = cst + n * 6;
    float e1x = cr[1], e1y = cr[2], e1z = cr[3], kp = cr[4], ksc = cr[5];
    float* orow = out + (size_t)(R0 + n) * 256;
#pragma unroll
    for (int ct = 0; ct < 4; ++ct) {
      int w = ct * 16 + (lane & 15);
      float vx = kp * (e1x * gB[ct][reg] + gC[0][ct][reg]) + ksc * scv[0][ct][reg];
      float vy = kp * (e1y * gB[ct][reg] + gC[1][ct][reg]) + ksc * scv[1][ct][reg];
      float vz = kp * (e1z * gB[ct][reg] + gC[2][ct][reg]) + ksc * scv[2][ct][reg];
      float* vp = orow + 64 + 3 * w;
      vp[0] = vx; vp[1] = vy; vp[2] = vz;
    }
  }
}

extern "C" void kernel_launch(void* const* d_in, const int* in_sizes, int n_in,
                              void* d_out, int out_size, void* d_ws, size_t ws_size,
                              hipStream_t stream) {
  const float* x1   = (const float*)d_in[0];
  const float* edge = (const float*)d_in[1];
  const float* tp   = (const float*)d_in[2];
  const float* node = (const float*)d_in[3];
  short* ws = (short*)d_ws;  // 128 KiB
  int n = in_sizes[0] / 256;

  // mats: 0=W_sc_s 1=W_lin0_s 2=W_sc_v 3=W_lin0_v 4=W_lin_A 5=W_lin_D 6=W_lin_B 7=W_lin_C
  prep_w<<<16, 256, 0, stream>>>(
      (const float*)d_in[6], (const float*)d_in[4],
      (const float*)d_in[7], (const float*)d_in[5],
      (const float*)d_in[8], (const float*)d_in[9],
      (const float*)d_in[10], (const float*)d_in[11], ws);

  fused_tp<<<n / 64, 256, 0, stream>>>(x1, edge, tp, node, ws, (float*)d_out);
}